// Round 19
// baseline (110.997 us; speedup 1.0000x reference)
//
#include <hip/hip_runtime.h>
#include <math.h>

// Problem constants: B=4, C=128, H=W=96, E=4, C8=16, scale=2 (baked in)
#define Bn 4
#define Cc 128
#define Hh 96
#define Ww 96
#define H2c 192
#define W2c 192
#define HW (Hh*Ww)
#define HW2 (H2c*W2c)

// Workspace: floats [0,16) = per-class taps {tx,ty,Dx,Dy};
//            ushort Mw at float-offset 16: M[cls][c_out][128] (We*Wc + I, bf16)
#define TAP_OFF 0
#define M_OFF 16

typedef float  f32x4  __attribute__((ext_vector_type(4)));
typedef short  s16x8  __attribute__((ext_vector_type(8)));
typedef unsigned int u32x4 __attribute__((ext_vector_type(4)));

__device__ __forceinline__ unsigned f2bf(float f) {
    unsigned u = __float_as_uint(f);
    return (u + 0x7FFFu + ((u >> 16) & 1u)) >> 16;   // RNE to bf16
}

// ---------------------------------------------------------------------------
// K1 (fused, verified r15-r17): per-class MLP -> taps AND
// M[cls] = We_mix*Wc_mix + I from GLOBAL wcomp/wexp. 64 blocks x 256 threads.
__global__ __launch_bounds__(256) void k1_prep(
    const float* __restrict__ wcomp, const float* __restrict__ wexp,
    const float* __restrict__ bw1, const float* __restrict__ bb1,
    const float* __restrict__ bw2, const float* __restrict__ bb2,
    const float* __restrict__ rw,  const float* __restrict__ rb,
    const float* __restrict__ ow,  const float* __restrict__ ob,
    float* __restrict__ ws, unsigned short* __restrict__ Mw)
{
    __shared__ float e1[64], e2[64], rr4[4], of2[2];
    const int tid   = threadIdx.x;
    const int cls   = blockIdx.x >> 4;
    const int chunk = blockIdx.x & 15;
    const float chv = (cls & 2) ? 0.25f : -0.25f;
    const float cwv = (cls & 1) ? 0.25f : -0.25f;

    if (tid < 64) {
        float h = bw1[tid*3+0]*0.5f + bw1[tid*3+1]*chv + bw1[tid*3+2]*cwv + bb1[tid];
        e1[tid] = fmaxf(h, 0.f);
    }
    __syncthreads();
    if (tid < 64) {
        float s = bb2[tid];
        for (int i = 0; i < 64; ++i) s += bw2[tid*64+i]*e1[i];
        e2[tid] = fmaxf(s, 0.f);
    }
    __syncthreads();
    if (tid < 6) {
        if (tid < 4) {
            float s = rb[tid];
            for (int i = 0; i < 64; ++i) s += rw[tid*64+i]*e2[i];
            rr4[tid] = 1.f/(1.f+expf(-s));
        } else {
            const int d = tid - 4;
            float s = ob[d];
            for (int i = 0; i < 64; ++i) s += ow[d*64+i]*e2[i];
            of2[d] = s;
        }
    }
    __syncthreads();
    const float r0 = rr4[0], r1 = rr4[1], r2 = rr4[2], r3 = rr4[3];

    if (chunk == 0 && tid == 0) {
        const float fx = cwv + of2[0];
        const float fy = chv + of2[1];
        const float Dx = floorf(fx), Dy = floorf(fy);
        ws[TAP_OFF + cls*4 + 0] = fx - Dx;
        ws[TAP_OFF + cls*4 + 1] = fy - Dy;
        ws[TAP_OFF + cls*4 + 2] = Dx;
        ws[TAP_OFF + cls*4 + 3] = Dy;
    }

    // M slice: thread -> (co, ci0..+3). wexp[e][c][o]: e*2048+c*16+o;
    // wcomp[e][o][c]: e*2048+o*128+c.
    const int co  = chunk*8 + (tid >> 5);
    const int ci0 = (tid & 31) * 4;
    const float* weB = wexp + co*16;
    float wem[16];
    #pragma unroll
    for (int o = 0; o < 16; ++o)
        wem[o] = r0*weB[o] + r1*weB[2048+o] + r2*weB[4096+o] + r3*weB[6144+o];
    float m[4];
    #pragma unroll
    for (int q = 0; q < 4; ++q) {
        const int ci = ci0 + q;
        const float* wcB = wcomp + ci;
        float s = 0.f;
        #pragma unroll
        for (int o = 0; o < 16; ++o) {
            const float wcm = r0*wcB[o*128]        + r1*wcB[2048 + o*128]
                            + r2*wcB[4096 + o*128] + r3*wcB[6144 + o*128];
            s += wem[o]*wcm;
        }
        if (co == ci) s += 1.f;
        m[q] = s;
    }
    uint2 v;
    v.x = f2bf(m[0]) | (f2bf(m[1]) << 16);
    v.y = f2bf(m[2]) | (f2bf(m[3]) << 16);
    *reinterpret_cast<uint2*>(Mw + (size_t)cls*16384 + co*128 + ci0) = v;
}

// Edge remap (verified rounds 1-18).
__device__ __forceinline__ void remap_axis(int c0, int last, float w0, float w1,
                                           int& base, float& a0, float& a1)
{
    base = min(max(c0, 0), last - 1);
    if (c0 >= 0 && c0 < last) { a0 = w0;  a1 = w1;  }
    else if (c0 == -1)        { a0 = w1;  a1 = 0.f; }
    else if (c0 == last)      { a0 = 0.f; a1 = w0;  }
    else                      { a0 = 0.f; a1 = 0.f; }
}

// ---------------------------------------------------------------------------
// K2: BARRIER-FREE wave-independent tiles. 2304 blocks x 256 threads; each of
// the 4 waves independently handles one CLASS of the same 16 half-res pixels
// (16 consecutive cols of one row; 96 = 6x16, no wrap). NO LDS, NO barriers.
// Lane (lo,hi): computes fea for pixel lo, channels hi*8+[0,8) per 32-ch
// k-slice -- exactly the MFMA A-fragment layout (r13's verified operand
// swap), so fea goes tap-regs -> pack -> mfma with no transpose.
// B = M rows from global (L2-hot, r13-verbatim addressing).
__global__ __launch_bounds__(256, 4) void k2_wave(
    const float* __restrict__ x, const float* __restrict__ wsr,
    const unsigned short* __restrict__ Mw, float* __restrict__ out)
{
    const int tid = threadIdx.x;
    const int l   = tid & 63;
    const int wv  = tid >> 6;
    const int lo  = l & 15, hi = l >> 4;

    // XCD swizzle: 2304 = 8 XCDs * 288; block = one 16-px group (all 4
    // classes via its 4 waves -> shared window lines, complementary stores).
    const int n  = blockIdx.x;
    const int w  = (n & 7)*288 + (n >> 3);     // 0..2303
    const int b  = w / 576;
    const int r_ = w % 576;
    const int j  = r_ / 6;                     // half-res row
    const int i0 = (r_ % 6) * 16;              // half-res col base
    const int cls = wv;                        // wave = class
    const int pyc = (cls >> 1) & 1, pxc = cls & 1;

    // ---- taps (wave-uniform scalars) ----
    const float tx = wsr[TAP_OFF + cls*4 + 0];
    const float ty = wsr[TAP_OFF + cls*4 + 1];
    const int   Dx = (int)wsr[TAP_OFF + cls*4 + 2];
    const int   Dy = (int)wsr[TAP_OFF + cls*4 + 3];

    // ---- per-lane pixel geometry (pixel index = lo) ----
    const int i = i0 + lo;
    int cb, rbw; float ax0, ax1, ay0, ay1;
    remap_axis(i + Dx, Ww - 1, 1.f - tx, tx, cb,  ax0, ax1);
    remap_axis(j + Dy, Hh - 1, 1.f - ty, ty, rbw, ay0, ay1);
    const float w00 = ay0*ax0, w01 = ay0*ax1, w10 = ay1*ax0, w11 = ay1*ax1;
    const float* xbp = x + (size_t)b*Cc*HW + (size_t)rbw*Ww + cb;

    const unsigned short* Mc = Mw + (size_t)cls*16384;

    f32x4 acc[8];
    #pragma unroll
    for (int cot = 0; cot < 8; ++cot) acc[cot] = (f32x4){0.f,0.f,0.f,0.f};

    // ---- 4 k-slices: 32 batched tap loads -> fea frag -> 8 MFMA ----
    #pragma unroll
    for (int s = 0; s < 4; ++s) {
        const int chb = s*32 + hi*8;       // this lane's 8 channels (A-frag k)
        float t00[8], t01[8], t10[8], t11[8];
        #pragma unroll
        for (int cc = 0; cc < 8; ++cc) {
            const float* p = xbp + (size_t)(chb + cc)*HW;
            t00[cc] = p[0]; t01[cc] = p[1]; t10[cc] = p[Ww]; t11[cc] = p[Ww+1];
        }
        float f[8];
        #pragma unroll
        for (int cc = 0; cc < 8; ++cc)
            f[cc] = w00*t00[cc] + w01*t01[cc] + w10*t10[cc] + w11*t11[cc];

        u32x4 u;
        u.x = f2bf(f[0]) | (f2bf(f[1]) << 16);
        u.y = f2bf(f[2]) | (f2bf(f[3]) << 16);
        u.z = f2bf(f[4]) | (f2bf(f[5]) << 16);
        u.w = f2bf(f[6]) | (f2bf(f[7]) << 16);
        const s16x8 af = __builtin_bit_cast(s16x8, u);

        s16x8 mf[8];
        #pragma unroll
        for (int cot = 0; cot < 8; ++cot)
            mf[cot] = *reinterpret_cast<const s16x8*>(
                Mc + (cot*16 + lo)*128 + chb);

        #pragma unroll
        for (int cot = 0; cot < 8; ++cot)
            acc[cot] = __builtin_amdgcn_mfma_f32_16x16x32_bf16(
                af, mf[cot], acc[cot], 0, 0, 0);
    }

    // ---- stores (r13's verified D mapping: col=ch=lo-idx, row=px=hi*4+r) ----
    const int yg = 2*j + pyc;
    float* obase = out + ((size_t)(b*Cc)*H2c + yg)*W2c;
    #pragma unroll
    for (int cot = 0; cot < 8; ++cot) {
        const int ch = cot*16 + lo;
        float* oc = obase + (size_t)ch*HW2;
        #pragma unroll
        for (int r = 0; r < 4; ++r) {
            const int xg = 2*(i0 + hi*4 + r) + pxc;
            oc[xg] = acc[cot][r];
        }
    }
}

extern "C" void kernel_launch(void* const* d_in, const int* in_sizes, int n_in,
                              void* d_out, int out_size, void* d_ws, size_t ws_size,
                              hipStream_t stream) {
    const float* x     = (const float*)d_in[0];
    const float* wcomp = (const float*)d_in[1];
    const float* wexp  = (const float*)d_in[2];
    const float* bw1   = (const float*)d_in[3];
    const float* bb1   = (const float*)d_in[4];
    const float* bw2   = (const float*)d_in[5];
    const float* bb2   = (const float*)d_in[6];
    const float* rw    = (const float*)d_in[7];
    const float* rb    = (const float*)d_in[8];
    const float* ow    = (const float*)d_in[9];
    const float* ob    = (const float*)d_in[10];
    float* out = (float*)d_out;
    float* ws  = (float*)d_ws;
    unsigned short* Mw = (unsigned short*)(ws + M_OFF);   // ~128 KB used

    k1_prep<<<64, 256, 0, stream>>>(wcomp, wexp, bw1, bb1, bw2, bb2,
                                    rw, rb, ow, ob, ws, Mw);
    k2_wave<<<2304, 256, 0, stream>>>(x, ws, Mw, out);
}